// Round 1
// baseline (596.524 us; speedup 1.0000x reference)
//
#include <hip/hip_runtime.h>
#include <math.h>

// Problem constants (from reference)
#define NN 100000   // N
#define MM 1000     // M
#define TPB 256     // threads per block
#define NPT 4       // n's per thread (float4)
#define NTILE (TPB*NPT)          // 1024 n per block
#define MB 16                    // m-tiles
#define MT ((MM + MB - 1) / MB)  // 63 m per tile

// out0[m*N + n] = sum_k Z[m][k] * W[n][k]   (rank-12 factored form)
__global__ __launch_bounds__(TPB) void desmo_main(
    const float* __restrict__ phi,       // (2, N)
    const float* __restrict__ pod,       // (N, 2)
    const float* __restrict__ c_coef,    // (6,)
    const float* __restrict__ z_values,  // (6, M)
    const float* __restrict__ zsin,      // (2, M)
    const float* __restrict__ zcos,      // (2, M)
    const float* __restrict__ ztanh,     // (2, M)
    const float* __restrict__ sin_coef,  // (2,)
    const float* __restrict__ cos_coef,  // (2,)
    const float* __restrict__ tanh_coef, // (2,)
    const float* __restrict__ omega,     // (6,)
    float* __restrict__ out0)            // (M, N)
{
    __shared__ float ZL[MT * 12];

    const int m0   = blockIdx.y * MT;
    const int mcnt = min(MT, MM - m0);

    // Cooperatively build the Z tile: ZL[ml*12 + k]
    for (int idx = threadIdx.x; idx < mcnt * 12; idx += TPB) {
        const int ml = idx / 12;
        const int k  = idx - ml * 12;
        const int m  = m0 + ml;
        float v;
        if (k < 6)       v = z_values[k * MM + m];
        else if (k < 8)  v = sin_coef[k - 6]   * zsin [(k - 6)  * MM + m];
        else if (k < 10) v = cos_coef[k - 8]   * zcos [(k - 8)  * MM + m];
        else             v = tanh_coef[k - 10] * ztanh[(k - 10) * MM + m];
        ZL[idx] = v;
    }
    __syncthreads();

    const int n0 = blockIdx.x * NTILE + threadIdx.x * NPT;
    if (n0 >= NN) return;  // N % 4 == 0, so a thread is either fully valid or fully out

    // ---- per-n W vectors (registers), 4 n's per thread ----
    const float4 ph0 = *(const float4*)(phi + n0);        // phi[0, n0..n0+3]
    const float4 ph1 = *(const float4*)(phi + NN + n0);   // phi[1, n0..n0+3]
    const float4 pa  = *(const float4*)(pod + 2 * n0);      // POD[n0..n0+1, :]
    const float4 pb  = *(const float4*)(pod + 2 * n0 + 4);  // POD[n0+2..n0+3, :]

    float y0[4] = { ph0.x * pa.x, ph0.y * pa.z, ph0.z * pb.x, ph0.w * pb.z };
    float y1[4] = { ph1.x * pa.y, ph1.y * pa.w, ph1.z * pb.y, ph1.w * pb.w };

    const float c0 = c_coef[0], c1 = c_coef[1], c2 = c_coef[2];
    const float c3 = c_coef[3], c4 = c_coef[4], c5 = c_coef[5];
    const float om0 = omega[0], om1 = omega[1], om2 = omega[2];
    const float om3 = omega[3], om4 = omega[4], om5 = omega[5];

    float W[12][4];
    #pragma unroll
    for (int j = 0; j < 4; ++j) {
        W[0][j]  = c0;
        W[1][j]  = c1 * y0[j];
        W[2][j]  = c2 * y1[j];
        W[3][j]  = c3 * y0[j] * y0[j];
        W[4][j]  = c4 * y0[j] * y1[j];
        W[5][j]  = c5 * y1[j] * y1[j];
        W[6][j]  = sinf(om0 * y0[j]);
        W[7][j]  = sinf(om3 * y1[j]);
        W[8][j]  = cosf(om1 * y0[j]);
        W[9][j]  = cosf(om4 * y1[j]);
        W[10][j] = tanhf(om2 * y0[j]);
        W[11][j] = tanhf(om5 * y1[j]);
    }

    // ---- main loop over m tile: broadcast Z from LDS, write float4 rows ----
    float* outp = out0 + (size_t)m0 * NN + n0;
    const float4* zl = (const float4*)ZL;
    for (int ml = 0; ml < mcnt; ++ml) {
        const float4 za = zl[ml * 3 + 0];
        const float4 zb = zl[ml * 3 + 1];
        const float4 zc = zl[ml * 3 + 2];
        float acc[4];
        #pragma unroll
        for (int j = 0; j < 4; ++j) {
            float a =  za.x * W[0][j];
            a += za.y * W[1][j];
            a += za.z * W[2][j];
            a += za.w * W[3][j];
            a += zb.x * W[4][j];
            a += zb.y * W[5][j];
            a += zb.z * W[6][j];
            a += zb.w * W[7][j];
            a += zc.x * W[8][j];
            a += zc.y * W[9][j];
            a += zc.z * W[10][j];
            a += zc.w * W[11][j];
            acc[j] = a;
        }
        float4 st = { acc[0], acc[1], acc[2], acc[3] };
        *(float4*)outp = st;
        outp += NN;
    }
}

// out1 = latent_spatial (N,2): out1[n,r] = phi[r,n]*POD[n,r]
// out2 = z_values copy (6*M)
__global__ __launch_bounds__(TPB) void desmo_aux(
    const float* __restrict__ phi,
    const float* __restrict__ pod,
    const float* __restrict__ z_values,
    float* __restrict__ out1,
    float* __restrict__ out2)
{
    const int n = blockIdx.x * TPB + threadIdx.x;
    if (n < NN) {
        float2 v;
        v.x = phi[n]      * pod[2 * n];
        v.y = phi[NN + n] * pod[2 * n + 1];
        *(float2*)(out1 + 2 * n) = v;
    }
    if (n < 6 * MM) out2[n] = z_values[n];
}

extern "C" void kernel_launch(void* const* d_in, const int* in_sizes, int n_in,
                              void* d_out, int out_size, void* d_ws, size_t ws_size,
                              hipStream_t stream) {
    // input order: X, phi, POD_modes, c_coef, z_values, zsin, zcos, ztanh,
    //              sin_coef, cos_coef, tanh_coef, omega   (X is unused)
    const float* phi       = (const float*)d_in[1];
    const float* pod       = (const float*)d_in[2];
    const float* c_coef    = (const float*)d_in[3];
    const float* z_values  = (const float*)d_in[4];
    const float* zsin      = (const float*)d_in[5];
    const float* zcos      = (const float*)d_in[6];
    const float* ztanh     = (const float*)d_in[7];
    const float* sin_coef  = (const float*)d_in[8];
    const float* cos_coef  = (const float*)d_in[9];
    const float* tanh_coef = (const float*)d_in[10];
    const float* omega     = (const float*)d_in[11];

    float* out0 = (float*)d_out;                       // (M, N) = 1e8
    float* out1 = out0 + (size_t)NN * MM;              // (N, 2)
    float* out2 = out1 + (size_t)NN * 2;               // (6, M)

    // aux: latent + z copy (tiny)
    {
        dim3 grid((NN + TPB - 1) / TPB);
        desmo_aux<<<grid, TPB, 0, stream>>>(phi, pod, z_values, out1, out2);
    }
    // main: (M, N) reconstruction
    {
        dim3 grid((NN + NTILE - 1) / NTILE, MB);  // (98, 16) = 1568 blocks
        desmo_main<<<grid, TPB, 0, stream>>>(phi, pod, c_coef, z_values,
                                             zsin, zcos, ztanh,
                                             sin_coef, cos_coef, tanh_coef,
                                             omega, out0);
    }
}